// Round 13
// baseline (287.658 us; speedup 1.0000x reference)
//
#include <hip/hip_runtime.h>
#include <cstddef>
#include <cstdint>
#include <math.h>

#define S_LEN 2048
#define DIM 1024
#define NH 16
#define HD 64

typedef __attribute__((ext_vector_type(8))) short bf16x8;
typedef __attribute__((ext_vector_type(8))) unsigned short u16x8;
typedef __attribute__((ext_vector_type(4))) float f32x4;

__device__ inline unsigned short f2bf(float x) {
  union { float f; unsigned u; } v; v.f = x;
  unsigned r = v.u + 0x7FFFu + ((v.u >> 16) & 1u);   // round-to-nearest-even
  return (unsigned short)(r >> 16);
}
__device__ inline float bf2f(unsigned short x) {
  union { unsigned u; float f; } v; v.u = ((unsigned)x) << 16; return v.f;
}
// pack two f32 -> two bf16 (truncation) in one v_perm_b32: out = {hi.bf16, lo.bf16}
__device__ inline unsigned pack_bf16_trunc(float hi, float lo) {
  union { float f; unsigned u; } a, b;
  a.f = hi; b.f = lo;
  return __builtin_amdgcn_perm(a.u, b.u, 0x07060302u);
}

#define GLOAD_LDS16(g, l)                                              \
  __builtin_amdgcn_global_load_lds(                                    \
      (const __attribute__((address_space(1))) void*)(g),              \
      (__attribute__((address_space(3))) void*)(l), 16, 0, 0)

// ---------------------------------------------------------------------------
// conv kernel: y=0..5 plain fp32->bf16 (real, imag, Wv_r, Wv_i, Wo_r, Wo_i).
// y=6: misc precompute (rope table, doubled phase table, folded biases).
// y=7..10: entangle-fold of Wq_r/Wk_r/Wq_i/Wk_i (d-major, 1x read amp).
// ---------------------------------------------------------------------------
struct ConvBatch {
  const float* src[6];
  unsigned short* dst[6];
  int n[6];
};

__global__ __launch_bounds__(256) void conv_kernel(
    ConvBatch cb, const float* __restrict__ E,
    const float* __restrict__ freqs, const float* __restrict__ phase,
    const float* __restrict__ bq_r, const float* __restrict__ bk_r,
    const float* __restrict__ bq_i, const float* __restrict__ bk_i,
    const float* __restrict__ Wq_r, const float* __restrict__ Wk_r,
    const float* __restrict__ Wq_i, const float* __restrict__ Wk_i,
    unsigned short* __restrict__ Wb,
    float* __restrict__ biasf, float2* __restrict__ ropeTab,
    float2* __restrict__ phaseTab2)
{
  const int t = threadIdx.x;
  const int y = blockIdx.y;

  if (y == 6) {   // misc precompute slice
    __shared__ float Es[NH * NH];
    Es[t] = E[t];
    __syncthreads();
    const int idx = blockIdx.x * 256 + t;
    if (idx < 32768) {
      const int s = idx >> 4, j = idx & 15;
      float sn, cs;
      sincosf((float)s * freqs[j], &sn, &cs);
      ropeTab[idx] = make_float2(cs, sn);
    } else if (idx < 32768 + 1024) {
      const int k = idx - 32768;
      float sn, cs;
      sincosf(2.f * phase[k], &sn, &cs);
      phaseTab2[k] = make_float2(cs, sn);
    } else if (idx < 32768 + 1024 + 4096) {
      const int i = idx - 33792;
      const int tz = i >> 10, nn = i & 1023;
      const int x = nn >> 6, d = nn & 63;
      const float* b = (tz == 0) ? bq_r : (tz == 1) ? bk_r : (tz == 2) ? bq_i : bk_i;
      float acc = 0.f;
#pragma unroll
      for (int h = 0; h < NH; h++) acc += Es[h * NH + x] * b[h * 64 + d];
      biasf[i] = acc;
    }
    return;
  }

  if (y >= 7) {   // entangle-fold slices, wi = y-7
    if (blockIdx.x >= 64) return;
    __shared__ float Es2[NH * NH];
    Es2[t] = E[t];
    __syncthreads();
    const int d  = blockIdx.x;
    const int wi = y - 7;
    const float* src = (wi == 0) ? Wq_r : (wi == 1) ? Wk_r : (wi == 2) ? Wq_i : Wk_i;
    const int slot   = (wi == 0) ? 0 : (wi == 1) ? 1 : (wi == 2) ? 3 : 4;
    unsigned short* dst = Wb + (size_t)slot * DIM * DIM;

    const int k0 = t * 4;
    float4 in[NH];
#pragma unroll
    for (int h = 0; h < NH; h++)
      in[h] = *(const float4*)(src + ((size_t)(h * 64 + d) << 10) + k0);

#pragma unroll
    for (int x = 0; x < NH; x++) {
      float ax = 0.f, ay = 0.f, az = 0.f, aw = 0.f;
#pragma unroll
      for (int h = 0; h < NH; h++) {
        const float e = Es2[h * NH + x];
        ax += e * in[h].x; ay += e * in[h].y;
        az += e * in[h].z; aw += e * in[h].w;
      }
      ushort4 o;
      o.x = f2bf(ax); o.y = f2bf(ay); o.z = f2bf(az); o.w = f2bf(aw);
      *(ushort4*)(dst + ((size_t)(x * 64 + d) << 10) + k0) = o;
    }
    return;
  }

  const int flat = (blockIdx.x * 256 + t) * 8;
  if (flat >= cb.n[y]) return;
  const float* s = cb.src[y];
  float4 a = *(const float4*)(s + flat);
  float4 b = *(const float4*)(s + flat + 4);
  u16x8 o;
  o[0] = f2bf(a.x); o[1] = f2bf(a.y); o[2] = f2bf(a.z); o[3] = f2bf(a.w);
  o[4] = f2bf(b.x); o[5] = f2bf(b.y); o[6] = f2bf(b.z); o[7] = f2bf(b.w);
  *(u16x8*)(cb.dst[y] + flat) = o;
}

// ---------------------------------------------------------------------------
// bf16 MFMA GEMM: C = A @ W^T + bias. Output modes (per z):
//   0: fp32 row-major (s, DIM)
//   2: bf16 transposed head-major [h][d][s]   (V)
//   3: bf16 head-major [h][s][d] + fused RoPE (fp32, shfl_xor pair mix) (Q,K)
// ---------------------------------------------------------------------------
struct BGemm {
  const unsigned short* A[6];
  const unsigned short* W[6];
  const float* bias[6];
  void* C[6];
  int mode[6];
  const float2* ropeTab;
};

__global__ __launch_bounds__(256) void gemm_mfma_kernel(BGemm gb)
{
  constexpr int K = DIM;
  const int z = blockIdx.z;
  const unsigned short* __restrict__ A = gb.A[z];
  const unsigned short* __restrict__ W = gb.W[z];
  const float* __restrict__ bias = gb.bias[z];
  const int mode = gb.mode[z];

  __shared__ __align__(16) unsigned short As[128 * 32];
  __shared__ __align__(16) unsigned short Ws[128 * 32];

  const int t    = threadIdx.x;
  const int lane = t & 63;
  const int w    = t >> 6;
  const int wm   = w >> 1, wn = w & 1;
  const int quad = lane >> 4, lcol = lane & 15;
  const int m0   = blockIdx.y * 128;
  const int n0   = blockIdx.x * 128;

  const int srow = t >> 2;
  const int sk8  = (t & 3) * 8;

  f32x4 acc[4][4];
#pragma unroll
  for (int i = 0; i < 4; i++)
#pragma unroll
    for (int j = 0; j < 4; j++)
#pragma unroll
      for (int r = 0; r < 4; r++) acc[i][j][r] = 0.f;

  for (int k0 = 0; k0 < K; k0 += 32) {
    __syncthreads();
#pragma unroll
    for (int p = 0; p < 2; p++) {
      const unsigned short* ga = A + (size_t)(m0 + p * 64 + srow) * K + k0 + sk8;
      GLOAD_LDS16(ga, As + (size_t)(p * 256 + w * 64) * 8);
      const unsigned short* gw = W + (size_t)(n0 + p * 64 + srow) * K + k0 + sk8;
      GLOAD_LDS16(gw, Ws + (size_t)(p * 256 + w * 64) * 8);
    }
    __syncthreads();

    bf16x8 af[4], bfr[4];
#pragma unroll
    for (int mi = 0; mi < 4; mi++)
      af[mi] = *(const bf16x8*)&As[(wm * 64 + mi * 16 + lcol) * 32 + quad * 8];
#pragma unroll
    for (int ni = 0; ni < 4; ni++)
      bfr[ni] = *(const bf16x8*)&Ws[(wn * 64 + ni * 16 + lcol) * 32 + quad * 8];
#pragma unroll
    for (int mi = 0; mi < 4; mi++)
#pragma unroll
      for (int ni = 0; ni < 4; ni++)
        acc[mi][ni] = __builtin_amdgcn_mfma_f32_16x16x32_bf16(af[mi], bfr[ni], acc[mi][ni], 0, 0, 0);
  }

#pragma unroll
  for (int mi = 0; mi < 4; mi++) {
#pragma unroll
    for (int ni = 0; ni < 4; ni++) {
#pragma unroll
      for (int r = 0; r < 4; r++) {
        const int grow = m0 + wm * 64 + mi * 16 + quad * 4 + r;
        const int gcol = n0 + wn * 64 + ni * 16 + lcol;
        float v = acc[mi][ni][r] + bias[gcol];
        if (mode == 3) {
          const float vp = __shfl_xor(v, 1);   // partner column (gcol^1)
          const int d = gcol & 63;
          if (d < 32) {
            const float2 cs = gb.ropeTab[grow * 16 + (d >> 1)];
            v = (d & 1) ? (v * cs.x + vp * cs.y)
                        : (v * cs.x - vp * cs.y);
          }
        }
        if (mode == 0) {
          ((float*)gb.C[z])[(size_t)grow * DIM + gcol] = v;
        } else if (mode == 2) {
          const int hh = gcol >> 6, d = gcol & 63;
          ((unsigned short*)gb.C[z])[((size_t)hh * HD + d) * S_LEN + grow] = f2bf(v);
        } else {
          const int hh = gcol >> 6, d = gcol & 63;
          ((unsigned short*)gb.C[z])[((size_t)hh * S_LEN + grow) * HD + d] = f2bf(v);
        }
      }
    }
  }
}

// ---------------------------------------------------------------------------
// Flash attention, transposed scores, QUARTER-SPLIT kv with static snake
// pairing: 2048 jobs (pair p = j>>2 -> itile = 31-(p>>4), h = p&15; quarter
// q = j&3 takes kv-chunk [n*q/4, n*(q+1)/4) of n = itile+1 tiles). Block b
// runs jobs {b, 2047-b}: total work = (32-g) + (g+1) = 33 quarter-tiles/4
// for EVERY block -> all 4 resident blocks/CU finish together (sustained
// 4 waves/SIMD, no atomics, no fences). Partials per quarter, bf16.
// ---------------------------------------------------------------------------
#define LDK 72

__global__ __launch_bounds__(256) void flash_mfma_kernel(
    const unsigned short* __restrict__ Qr, const unsigned short* __restrict__ Qi,
    const unsigned short* __restrict__ Kr, const unsigned short* __restrict__ Ki,
    const unsigned short* __restrict__ VtR, const unsigned short* __restrict__ VtI,
    unsigned short* __restrict__ OpR, unsigned short* __restrict__ OpI,
    float* __restrict__ Lp, const float2* __restrict__ phaseTab2,
    const float* __restrict__ p_is, const float* __restrict__ p_at,
    const float* __restrict__ p_ce)
{
  __shared__ __align__(16) unsigned short Krs[64 * LDK];
  __shared__ __align__(16) unsigned short Kis[64 * LDK];
  __shared__ __align__(16) unsigned short VTr[64 * LDK];
  __shared__ __align__(16) unsigned short VTi[64 * LDK];
  unsigned short* Ps = Krs;   // alias: Krs dead after scores (barrier-protected)

  const int t    = threadIdx.x;
  const int lane = t & 63;
  const int w    = t >> 6;
  const int quad = lane >> 4;
  const int lcol = lane & 15;

  const float strength = 1.f / (1.f + expf(-p_is[0]));
  const float temp     = fmaxf(expf(p_at[0]), 0.1f);
  const float cfac     = strength / temp;
  const float eps      = 0.03f / (1.f + expf(-p_ce[0]));
  const float c2       = 0.015625f * (1.f + eps * eps);
  const float cl       = cfac * 1.4426950408889634f;   // cfac * log2(e)
  const float c2e      = c2 * cl * cl;
  const float epse     = 1e-6f * cl * cl;

  const int srow = t >> 3;
  const int sd0  = (t & 7) * 8;
  const size_t SLsz = (size_t)S_LEN * DIM;

  for (int jj = 0; jj < 2; jj++) {
    const int job   = jj ? (2047 - (int)blockIdx.x) : (int)blockIdx.x;
    const int p     = job >> 2;
    const int q     = job & 3;
    const int itile = 31 - (p >> 4);
    const int h     = p & 15;
    const int i0    = itile * 64;
    const int n     = itile + 1;
    const int jbeg  = (n * q) >> 2;
    const int jend  = (n * (q + 1)) >> 2;

    const int qg = i0 + w * 16 + lcol;      // this lane's q (global row)

    // Q fragments from global, fused doubled-phase rotation (fp32 math)
    bf16x8 qrf[2], qif[2];
    {
      const size_t base_q = ((size_t)h * S_LEN + qg) * HD;
#pragma unroll
      for (int ks = 0; ks < 2; ks++) {
        bf16x8 r8 = *(const bf16x8*)(Qr + base_q + ks * 32 + quad * 8);
        bf16x8 i8 = *(const bf16x8*)(Qi + base_q + ks * 32 + quad * 8);
        bf16x8 orr, oii;
#pragma unroll
        for (int j = 0; j < 8; j++) {
          const float2 ph = phaseTab2[h * HD + ks * 32 + quad * 8 + j];
          const float qr = bf2f((unsigned short)r8[j]);
          const float qi = bf2f((unsigned short)i8[j]);
          orr[j] = (short)f2bf(qr * ph.x - qi * ph.y);
          oii[j] = (short)f2bf(qr * ph.y + qi * ph.x);
        }
        qrf[ks] = orr;
        qif[ks] = oii;
      }
    }

    float lsum = 0.f;
    f32x4 aOr[4], aOi[4];                 // O^T: d = cc*16+quad*4+r, q = lcol
#pragma unroll
    for (int cc = 0; cc < 4; cc++)
#pragma unroll
      for (int r = 0; r < 4; r++) { aOr[cc][r] = 0.f; aOi[cc][r] = 0.f; }

    bf16x8 pk[2], pki[2], pv[2], pvi[2];

    // stride-incremented prefetch pointers (start at tile jbeg)
    const unsigned short* pKr = Kr  + ((size_t)h * S_LEN + jbeg * 64 + srow) * HD + sd0;
    const unsigned short* pKi = Ki  + ((size_t)h * S_LEN + jbeg * 64 + srow) * HD + sd0;
    const unsigned short* pVr = VtR + ((size_t)h * HD + srow) * S_LEN + jbeg * 64 + sd0;
    const unsigned short* pVi = VtI + ((size_t)h * HD + srow) * S_LEN + jbeg * 64 + sd0;

    if (jbeg < jend) {
#pragma unroll
      for (int it = 0; it < 2; it++) {
        pk [it] = *(const bf16x8*)(pKr + (size_t)it * 32 * HD);
        pki[it] = *(const bf16x8*)(pKi + (size_t)it * 32 * HD);
        pv [it] = *(const bf16x8*)(pVr + (size_t)it * 32 * S_LEN);
        pvi[it] = *(const bf16x8*)(pVi + (size_t)it * 32 * S_LEN);
      }
    }

    for (int jt = jbeg; jt < jend; jt++) {
      __syncthreads();   // all waves done with previous tile's (or job's) LDS
#pragma unroll
      for (int it = 0; it < 2; it++) {
        const int row = srow + it * 32;
        *(bf16x8*)&Krs[row * LDK + sd0] = pk [it];
        *(bf16x8*)&Kis[row * LDK + sd0] = pki[it];
        *(bf16x8*)&VTr[row * LDK + sd0] = pv [it];
        *(bf16x8*)&VTi[row * LDK + sd0] = pvi[it];
      }
      __syncthreads();

      if (jt + 1 < jend) {
        pKr += 64 * HD; pKi += 64 * HD; pVr += 64; pVi += 64;
#pragma unroll
        for (int it = 0; it < 2; it++) {
          pk [it] = *(const bf16x8*)(pKr + (size_t)it * 32 * HD);
          pki[it] = *(const bf16x8*)(pKi + (size_t)it * 32 * HD);
          pv [it] = *(const bf16x8*)(pVr + (size_t)it * 32 * S_LEN);
          pvi[it] = *(const bf16x8*)(pVi + (size_t)it * 32 * S_LEN);
        }
      }

      // ---- scores (transposed): D[kv][q] via mfma(K, Q) ----
      f32x4 k1[4], k2[4], kx[4];
#pragma unroll
      for (int cc = 0; cc < 4; cc++)
#pragma unroll
        for (int r = 0; r < 4; r++) { k1[cc][r] = 0.f; k2[cc][r] = 0.f; kx[cc][r] = 0.f; }
#pragma unroll
      for (int ks = 0; ks < 2; ks++) {
#pragma unroll
        for (int cc = 0; cc < 4; cc++) {
          const int off = (cc * 16 + lcol) * LDK + ks * 32 + quad * 8;
          bf16x8 krf = *(const bf16x8*)&Krs[off];
          bf16x8 kif = *(const bf16x8*)&Kis[off];
          k1[cc] = __builtin_amdgcn_mfma_f32_16x16x32_bf16(krf, qrf[ks], k1[cc], 0, 0, 0);
          k2[cc] = __builtin_amdgcn_mfma_f32_16x16x32_bf16(kif, qif[ks], k2[cc], 0, 0, 0);
          kx[cc] = __builtin_amdgcn_mfma_f32_16x16x32_bf16(kif, qrf[ks], kx[cc], 0, 0, 0);
          kx[cc] = __builtin_amdgcn_mfma_f32_16x16x32_bf16(krf, qif[ks], kx[cc], 0, 0, 0);
        }
      }

      __syncthreads();   // Krs/Kis reads done before Ps overwrites

      // ---- no-max softmax: p = 2^sqrt(u*c2e + epse) ----
      const int prow = (w * 16 + lcol) * LDK;
      if (jt != itile) {             // bulk tiles: no mask ops
#pragma unroll
        for (int cc = 0; cc < 4; cc++) {
          float pv4[4];
#pragma unroll
          for (int r = 0; r < 4; r++) {
            const float a = k1[cc][r] - k2[cc][r];
            const float b = kx[cc][r];
            const float u = fmaf(b, b, a * a);
            const float pp = __builtin_amdgcn_exp2f(sqrtf(fmaf(u, c2e, epse)));
            pv4[r] = pp;
            lsum += pp;
          }
          uint2 packed;
          packed.x = pack_bf16_trunc(pv4[1], pv4[0]);
          packed.y = pack_bf16_trunc(pv4[3], pv4[2]);
          *(uint2*)&Ps[prow + cc * 16 + quad * 4] = packed;
        }
      } else {                        // diagonal tile: causal mask
        const int j0 = jt * 64;
#pragma unroll
        for (int cc = 0; cc < 4; cc++) {
          float pv4[4];
#pragma unroll
          for (int r = 0; r < 4; r++) {
            const float a = k1[cc][r] - k2[cc][r];
            const float b = kx[cc][r];
            const float u = fmaf(b, b, a * a);
            float pp = __builtin_amdgcn_exp2f(sqrtf(fmaf(u, c2e, epse)));
            const int gj = j0 + cc * 16 + quad * 4 + r;
            if (gj > qg) pp = 0.f;
            pv4[r] = pp;
            lsum += pp;
          }
          uint2 packed;
          packed.x = pack_bf16_trunc(pv4[1], pv4[0]);
          packed.y = pack_bf16_trunc(pv4[3], pv4[2]);
          *(uint2*)&Ps[prow + cc * 16 + quad * 4] = packed;
        }
      }

      // ---- PV: O^T = V^T P^T ----
#pragma unroll
      for (int ks = 0; ks < 2; ks++) {
        bf16x8 pf = *(const bf16x8*)&Ps[(w * 16 + lcol) * LDK + ks * 32 + quad * 8];
#pragma unroll
        for (int cc = 0; cc < 4; cc++) {
          const int off = (cc * 16 + lcol) * LDK + ks * 32 + quad * 8;
          bf16x8 vrf = *(const bf16x8*)&VTr[off];
          bf16x8 vif = *(const bf16x8*)&VTi[off];
          aOr[cc] = __builtin_amdgcn_mfma_f32_16x16x32_bf16(vrf, pf, aOr[cc], 0, 0, 0);
          aOi[cc] = __builtin_amdgcn_mfma_f32_16x16x32_bf16(vif, pf, aOi[cc], 0, 0, 0);
        }
      }
    }

    // ---- row sums: reduce lane partials across the 4 quads (same q) ----
    lsum += __shfl_xor(lsum, 16);
    lsum += __shfl_xor(lsum, 32);
    if (lane < 16)
      Lp[((size_t)q * NH + h) * S_LEN + qg] = lsum;

    // ---- epilogue: packed unnormalized bf16 partials (O^T -> row-major) ----
    const size_t rowbase = (size_t)q * SLsz + (size_t)qg * DIM + h * HD;
#pragma unroll
    for (int cc = 0; cc < 4; cc++) {
      const int d0 = cc * 16 + quad * 4;
      uint2 pr, pi;
      pr.x = pack_bf16_trunc(aOr[cc][1], aOr[cc][0]);
      pr.y = pack_bf16_trunc(aOr[cc][3], aOr[cc][2]);
      pi.x = pack_bf16_trunc(aOi[cc][1], aOi[cc][0]);
      pi.y = pack_bf16_trunc(aOi[cc][3], aOi[cc][2]);
      *(uint2*)(OpR + rowbase + d0) = pr;
      *(uint2*)(OpI + rowbase + d0) = pi;
    }
  }
}

// ---------------------------------------------------------------------------
// Combine kv-split quarters: O = (O0+O1+O2+O3)/(L0+L1+L2+L3), bf16 in/out.
// ---------------------------------------------------------------------------
__global__ __launch_bounds__(256) void combine_kernel(
    const unsigned short* __restrict__ OpR, const unsigned short* __restrict__ OpI,
    const float* __restrict__ Lp,
    unsigned short* __restrict__ Or, unsigned short* __restrict__ Oi)
{
  const size_t SLsz = (size_t)S_LEN * DIM;
  const int idx = blockIdx.x * 256 + threadIdx.x;
  const size_t e0 = (size_t)idx * 8;
  const int s = (int)(e0 >> 10);
  const int col = (int)(e0 & 1023);
  const int h = col >> 6;

  float L = 0.f;
#pragma unroll
  for (int q = 0; q < 4; q++)
    L += Lp[((size_t)q * NH + h) * S_LEN + s];
  const float inv = 1.f / L;

  float accR[8] = {}, accI[8] = {};
#pragma unroll
  for (int q = 0; q < 4; q++) {
    bf16x8 rq = *(const bf16x8*)(OpR + (size_t)q * SLsz + e0);
    bf16x8 iq = *(const bf16x8*)(OpI + (size_t)q * SLsz + e0);
#pragma unroll
    for (int j = 0; j < 8; j++) {
      accR[j] += bf2f((unsigned short)rq[j]);
      accI[j] += bf2f((unsigned short)iq[j]);
    }
  }

  u16x8 orv, oiv;
#pragma unroll
  for (int j = 0; j < 8; j++) {
    orv[j] = f2bf(accR[j] * inv);
    oiv[j] = f2bf(accI[j] * inv);
  }
  *(u16x8*)(Or + e0) = orv;
  *(u16x8*)(Oi + e0) = oiv;
}

// ---------------------------------------------------------------------------
extern "C" void kernel_launch(void* const* d_in, const int* in_sizes, int n_in,
                              void* d_out, int out_size, void* d_ws, size_t ws_size,
                              hipStream_t stream)
{
  const float* real = (const float*)d_in[0];
  const float* imag = (const float*)d_in[1];
  const float* Wq_r = (const float*)d_in[2];
  const float* bq_r = (const float*)d_in[3];
  const float* Wk_r = (const float*)d_in[4];
  const float* bk_r = (const float*)d_in[5];
  const float* Wv_r = (const float*)d_in[6];
  const float* bv_r = (const float*)d_in[7];
  const float* Wq_i = (const float*)d_in[8];
  const float* bq_i = (const float*)d_in[9];
  const float* Wk_i = (const float*)d_in[10];
  const float* bk_i = (const float*)d_in[11];
  const float* Wv_i = (const float*)d_in[12];
  const float* bv_i = (const float*)d_in[13];
  const float* Wo_r = (const float*)d_in[14];
  const float* bo_r = (const float*)d_in[15];
  const float* Wo_i = (const float*)d_in[16];
  const float* bo_i = (const float*)d_in[17];
  const float* phase = (const float*)d_in[18];
  const float* ent   = (const float*)d_in[19];
  const float* freqs = (const float*)d_in[20];
  const float* p_is  = (const float*)d_in[21];
  const float* p_at  = (const float*)d_in[22];
  const float* p_ce  = (const float*)d_in[23];

  unsigned short* ws = (unsigned short*)d_ws;
  const size_t SL = (size_t)S_LEN * DIM;
  const size_t WL = (size_t)DIM * DIM;

  unsigned short* realb = ws;
  unsigned short* imagb = realb + SL;
  unsigned short* Wb    = imagb + SL;        // 8 x WL
  unsigned short* q_r   = Wb + 8 * WL;
  unsigned short* k_r   = q_r + SL;
  unsigned short* v_r   = k_r + SL;          // [h][d][s]
  unsigned short* q_i   = v_r + SL;
  unsigned short* k_i   = q_i + SL;
  unsigned short* v_i   = k_i + SL;          // [h][d][s]
  unsigned short* OpR   = v_i + SL;          // 4 quarters x SL bf16
  unsigned short* OpI   = OpR + 4 * SL;

  float* fbase    = (float*)(OpI + 4 * SL);
  float* biasf    = fbase;                   // 4096
  float* ropeTab  = biasf + 4096;            // 32768 float2
  float* phaseTb2 = ropeTab + 65536;         // 1024 float2
  float* Lp       = phaseTb2 + 2048;         // 4 * NH * S_LEN

  unsigned short* O_r = q_r;   // reuse after flash
  unsigned short* O_i = q_i;

  float* out_r = (float*)d_out;
  float* out_i = out_r + SL;

  // 0. conversions + entangle-fold + tables + folded biases (one dispatch)
  ConvBatch cb;
  cb.src[0] = real;  cb.dst[0] = realb;        cb.n[0] = (int)SL;
  cb.src[1] = imag;  cb.dst[1] = imagb;        cb.n[1] = (int)SL;
  cb.src[2] = Wv_r;  cb.dst[2] = Wb + 2 * WL;  cb.n[2] = (int)WL;
  cb.src[3] = Wv_i;  cb.dst[3] = Wb + 5 * WL;  cb.n[3] = (int)WL;
  cb.src[4] = Wo_r;  cb.dst[4] = Wb + 6 * WL;  cb.n[4] = (int)WL;
  cb.src[5] = Wo_i;  cb.dst[5] = Wb + 7 * WL;  cb.n[5] = (int)WL;
  conv_kernel<<<dim3(1024, 11), dim3(256), 0, stream>>>(
      cb, ent, freqs, phase, bq_r, bk_r, bq_i, bk_i,
      Wq_r, Wk_r, Wq_i, Wk_i, Wb,
      biasf, (float2*)ropeTab, (float2*)phaseTb2);

  // 1. six projections: Q/K head-major + fused rope (mode 3), V transposed
  BGemm g1;
  g1.A[0] = realb; g1.A[1] = realb; g1.A[2] = realb;
  g1.A[3] = imagb; g1.A[4] = imagb; g1.A[5] = imagb;
  for (int i = 0; i < 6; i++) g1.W[i] = Wb + (size_t)i * WL;
  g1.bias[0] = biasf;        g1.bias[1] = biasf + 1024; g1.bias[2] = bv_r;
  g1.bias[3] = biasf + 2048; g1.bias[4] = biasf + 3072; g1.bias[5] = bv_i;
  g1.C[0] = q_r; g1.C[1] = k_r; g1.C[2] = v_r;
  g1.C[3] = q_i; g1.C[4] = k_i; g1.C[5] = v_i;
  g1.mode[0] = 3; g1.mode[1] = 3; g1.mode[2] = 2;
  g1.mode[3] = 3; g1.mode[4] = 3; g1.mode[5] = 2;
  g1.ropeTab = (const float2*)ropeTab;
  gemm_mfma_kernel<<<dim3(8, 16, 6), dim3(256), 0, stream>>>(g1);

  // 2. flash attention (quarter-split snake pairing) -> bf16 partials
  flash_mfma_kernel<<<dim3(1024), dim3(256), 0, stream>>>(
      q_r, q_i, k_r, k_i, v_r, v_i, OpR, OpI, Lp,
      (const float2*)phaseTb2, p_is, p_at, p_ce);

  // 3. combine quarters -> bf16 O
  combine_kernel<<<dim3(1024), dim3(256), 0, stream>>>(OpR, OpI, Lp, O_r, O_i);

  // 4. output projections -> fp32 d_out
  BGemm g2 = {};
  g2.A[0] = O_r; g2.A[1] = O_i;
  g2.W[0] = Wb + 6 * WL; g2.W[1] = Wb + 7 * WL;
  g2.bias[0] = bo_r; g2.bias[1] = bo_i;
  g2.C[0] = out_r; g2.C[1] = out_i;
  g2.mode[0] = 0; g2.mode[1] = 0;
  g2.ropeTab = (const float2*)ropeTab;
  gemm_mfma_kernel<<<dim3(8, 16, 2), dim3(256), 0, stream>>>(g2);
}

// Round 14
// 280.680 us; speedup vs baseline: 1.0249x; 1.0249x over previous
//
#include <hip/hip_runtime.h>
#include <cstddef>
#include <cstdint>
#include <math.h>

#define S_LEN 2048
#define DIM 1024
#define NH 16
#define HD 64

typedef __attribute__((ext_vector_type(8))) short bf16x8;
typedef __attribute__((ext_vector_type(8))) unsigned short u16x8;
typedef __attribute__((ext_vector_type(4))) float f32x4;

__device__ inline unsigned short f2bf(float x) {
  union { float f; unsigned u; } v; v.f = x;
  unsigned r = v.u + 0x7FFFu + ((v.u >> 16) & 1u);   // round-to-nearest-even
  return (unsigned short)(r >> 16);
}
__device__ inline float bf2f(unsigned short x) {
  union { unsigned u; float f; } v; v.u = ((unsigned)x) << 16; return v.f;
}
// pack two f32 -> two bf16 (truncation) in one v_perm_b32: out = {hi.bf16, lo.bf16}
__device__ inline unsigned pack_bf16_trunc(float hi, float lo) {
  union { float f; unsigned u; } a, b;
  a.f = hi; b.f = lo;
  return __builtin_amdgcn_perm(a.u, b.u, 0x07060302u);
}

#define GLOAD_LDS16(g, l)                                              \
  __builtin_amdgcn_global_load_lds(                                    \
      (const __attribute__((address_space(1))) void*)(g),              \
      (__attribute__((address_space(3))) void*)(l), 16, 0, 0)

// ---------------------------------------------------------------------------
// conv kernel: y=0..5 plain fp32->bf16 (real, imag, Wv_r, Wv_i, Wo_r, Wo_i).
// y=6: misc precompute (rope table, doubled phase table, folded biases).
// y=7..10: entangle-fold of Wq_r/Wk_r/Wq_i/Wk_i (d-major, 1x read amp).
// ---------------------------------------------------------------------------
struct ConvBatch {
  const float* src[6];
  unsigned short* dst[6];
  int n[6];
};

__global__ __launch_bounds__(256) void conv_kernel(
    ConvBatch cb, const float* __restrict__ E,
    const float* __restrict__ freqs, const float* __restrict__ phase,
    const float* __restrict__ bq_r, const float* __restrict__ bk_r,
    const float* __restrict__ bq_i, const float* __restrict__ bk_i,
    const float* __restrict__ Wq_r, const float* __restrict__ Wk_r,
    const float* __restrict__ Wq_i, const float* __restrict__ Wk_i,
    unsigned short* __restrict__ Wb,
    float* __restrict__ biasf, float2* __restrict__ ropeTab,
    float2* __restrict__ phaseTab2)
{
  const int t = threadIdx.x;
  const int y = blockIdx.y;

  if (y == 6) {   // misc precompute slice
    __shared__ float Es[NH * NH];
    Es[t] = E[t];
    __syncthreads();
    const int idx = blockIdx.x * 256 + t;
    if (idx < 32768) {
      const int s = idx >> 4, j = idx & 15;
      float sn, cs;
      sincosf((float)s * freqs[j], &sn, &cs);
      ropeTab[idx] = make_float2(cs, sn);
    } else if (idx < 32768 + 1024) {
      const int k = idx - 32768;
      float sn, cs;
      sincosf(2.f * phase[k], &sn, &cs);
      phaseTab2[k] = make_float2(cs, sn);
    } else if (idx < 32768 + 1024 + 4096) {
      const int i = idx - 33792;
      const int tz = i >> 10, nn = i & 1023;
      const int x = nn >> 6, d = nn & 63;
      const float* b = (tz == 0) ? bq_r : (tz == 1) ? bk_r : (tz == 2) ? bq_i : bk_i;
      float acc = 0.f;
#pragma unroll
      for (int h = 0; h < NH; h++) acc += Es[h * NH + x] * b[h * 64 + d];
      biasf[i] = acc;
    }
    return;
  }

  if (y >= 7) {   // entangle-fold slices, wi = y-7
    if (blockIdx.x >= 64) return;
    __shared__ float Es2[NH * NH];
    Es2[t] = E[t];
    __syncthreads();
    const int d  = blockIdx.x;
    const int wi = y - 7;
    const float* src = (wi == 0) ? Wq_r : (wi == 1) ? Wk_r : (wi == 2) ? Wq_i : Wk_i;
    const int slot   = (wi == 0) ? 0 : (wi == 1) ? 1 : (wi == 2) ? 3 : 4;
    unsigned short* dst = Wb + (size_t)slot * DIM * DIM;

    const int k0 = t * 4;
    float4 in[NH];
#pragma unroll
    for (int h = 0; h < NH; h++)
      in[h] = *(const float4*)(src + ((size_t)(h * 64 + d) << 10) + k0);

#pragma unroll
    for (int x = 0; x < NH; x++) {
      float ax = 0.f, ay = 0.f, az = 0.f, aw = 0.f;
#pragma unroll
      for (int h = 0; h < NH; h++) {
        const float e = Es2[h * NH + x];
        ax += e * in[h].x; ay += e * in[h].y;
        az += e * in[h].z; aw += e * in[h].w;
      }
      ushort4 o;
      o.x = f2bf(ax); o.y = f2bf(ay); o.z = f2bf(az); o.w = f2bf(aw);
      *(ushort4*)(dst + ((size_t)(x * 64 + d) << 10) + k0) = o;
    }
    return;
  }

  const int flat = (blockIdx.x * 256 + t) * 8;
  if (flat >= cb.n[y]) return;
  const float* s = cb.src[y];
  float4 a = *(const float4*)(s + flat);
  float4 b = *(const float4*)(s + flat + 4);
  u16x8 o;
  o[0] = f2bf(a.x); o[1] = f2bf(a.y); o[2] = f2bf(a.z); o[3] = f2bf(a.w);
  o[4] = f2bf(b.x); o[5] = f2bf(b.y); o[6] = f2bf(b.z); o[7] = f2bf(b.w);
  *(u16x8*)(cb.dst[y] + flat) = o;
}

// ---------------------------------------------------------------------------
// bf16 MFMA GEMM: C = A @ W^T + bias. Output modes (per z):
//   0: fp32 row-major (s, DIM)
//   2: bf16 transposed head-major [h][d][s]   (V)
//   3: bf16 head-major [h][s][d] + fused RoPE (fp32, shfl_xor pair mix) (Q,K)
// ---------------------------------------------------------------------------
struct BGemm {
  const unsigned short* A[6];
  const unsigned short* W[6];
  const float* bias[6];
  void* C[6];
  int mode[6];
  const float2* ropeTab;
};

__global__ __launch_bounds__(256) void gemm_mfma_kernel(BGemm gb)
{
  constexpr int K = DIM;
  const int z = blockIdx.z;
  const unsigned short* __restrict__ A = gb.A[z];
  const unsigned short* __restrict__ W = gb.W[z];
  const float* __restrict__ bias = gb.bias[z];
  const int mode = gb.mode[z];

  __shared__ __align__(16) unsigned short As[128 * 32];
  __shared__ __align__(16) unsigned short Ws[128 * 32];

  const int t    = threadIdx.x;
  const int lane = t & 63;
  const int w    = t >> 6;
  const int wm   = w >> 1, wn = w & 1;
  const int quad = lane >> 4, lcol = lane & 15;
  const int m0   = blockIdx.y * 128;
  const int n0   = blockIdx.x * 128;

  const int srow = t >> 2;
  const int sk8  = (t & 3) * 8;

  f32x4 acc[4][4];
#pragma unroll
  for (int i = 0; i < 4; i++)
#pragma unroll
    for (int j = 0; j < 4; j++)
#pragma unroll
      for (int r = 0; r < 4; r++) acc[i][j][r] = 0.f;

  for (int k0 = 0; k0 < K; k0 += 32) {
    __syncthreads();
#pragma unroll
    for (int p = 0; p < 2; p++) {
      const unsigned short* ga = A + (size_t)(m0 + p * 64 + srow) * K + k0 + sk8;
      GLOAD_LDS16(ga, As + (size_t)(p * 256 + w * 64) * 8);
      const unsigned short* gw = W + (size_t)(n0 + p * 64 + srow) * K + k0 + sk8;
      GLOAD_LDS16(gw, Ws + (size_t)(p * 256 + w * 64) * 8);
    }
    __syncthreads();

    bf16x8 af[4], bfr[4];
#pragma unroll
    for (int mi = 0; mi < 4; mi++)
      af[mi] = *(const bf16x8*)&As[(wm * 64 + mi * 16 + lcol) * 32 + quad * 8];
#pragma unroll
    for (int ni = 0; ni < 4; ni++)
      bfr[ni] = *(const bf16x8*)&Ws[(wn * 64 + ni * 16 + lcol) * 32 + quad * 8];
#pragma unroll
    for (int mi = 0; mi < 4; mi++)
#pragma unroll
      for (int ni = 0; ni < 4; ni++)
        acc[mi][ni] = __builtin_amdgcn_mfma_f32_16x16x32_bf16(af[mi], bfr[ni], acc[mi][ni], 0, 0, 0);
  }

#pragma unroll
  for (int mi = 0; mi < 4; mi++) {
#pragma unroll
    for (int ni = 0; ni < 4; ni++) {
#pragma unroll
      for (int r = 0; r < 4; r++) {
        const int grow = m0 + wm * 64 + mi * 16 + quad * 4 + r;
        const int gcol = n0 + wn * 64 + ni * 16 + lcol;
        float v = acc[mi][ni][r] + bias[gcol];
        if (mode == 3) {
          const float vp = __shfl_xor(v, 1);   // partner column (gcol^1)
          const int d = gcol & 63;
          if (d < 32) {
            const float2 cs = gb.ropeTab[grow * 16 + (d >> 1)];
            v = (d & 1) ? (v * cs.x + vp * cs.y)
                        : (v * cs.x - vp * cs.y);
          }
        }
        if (mode == 0) {
          ((float*)gb.C[z])[(size_t)grow * DIM + gcol] = v;
        } else if (mode == 2) {
          const int hh = gcol >> 6, d = gcol & 63;
          ((unsigned short*)gb.C[z])[((size_t)hh * HD + d) * S_LEN + grow] = f2bf(v);
        } else {
          const int hh = gcol >> 6, d = gcol & 63;
          ((unsigned short*)gb.C[z])[((size_t)hh * S_LEN + grow) * HD + d] = f2bf(v);
        }
      }
    }
  }
}

// ---------------------------------------------------------------------------
// Flash attention, transposed scores (D[kv][q] via mfma(K,Q)), kv HALF-split,
// no-max softmax. Complementary-pairs static mapping (CU = blockIdx mod 256,
// verified R5/R6): CU c (g=c>>4, h=c&15) hosts {itile 31-g half0/half1,
// itile g half0/half1} -> serial tile-work = (32-g)+(g+1) = 33 on EVERY CU,
// and both resident itiles share head h with nested kv ranges (L2 reuse).
// ---------------------------------------------------------------------------
#define LDK 72

__global__ __launch_bounds__(256) void flash_mfma_kernel(
    const unsigned short* __restrict__ Qr, const unsigned short* __restrict__ Qi,
    const unsigned short* __restrict__ Kr, const unsigned short* __restrict__ Ki,
    const unsigned short* __restrict__ VtR, const unsigned short* __restrict__ VtI,
    unsigned short* __restrict__ OpR, unsigned short* __restrict__ OpI,
    float* __restrict__ Lp, const float2* __restrict__ phaseTab2,
    const float* __restrict__ p_is, const float* __restrict__ p_at,
    const float* __restrict__ p_ce)
{
  __shared__ __align__(16) unsigned short Krs[64 * LDK];
  __shared__ __align__(16) unsigned short Kis[64 * LDK];
  __shared__ __align__(16) unsigned short VTr[64 * LDK];
  __shared__ __align__(16) unsigned short VTi[64 * LDK];
  unsigned short* Ps = Krs;   // alias: Krs dead after scores (barrier-protected)

  const int t    = threadIdx.x;
  const int lane = t & 63;
  const int w    = t >> 6;
  const int quad = lane >> 4;
  const int lcol = lane & 15;

  // complementary-pairs mapping (see header comment)
  const int bx    = blockIdx.x;
  const int c     = bx & 255;
  const int which = bx >> 8;           // 0..3
  const int h     = c & 15;
  const int g     = c >> 4;            // 0..15
  const int itile = (which < 2) ? (31 - g) : g;
  const int half  = which & 1;
  const int i0    = itile * 64;
  const int n     = itile + 1;
  const int jmid  = (n + 1) >> 1;
  const int jbeg  = half ? jmid : 0;
  const int jend  = half ? n : jmid;

  const float strength = 1.f / (1.f + expf(-p_is[0]));
  const float temp     = fmaxf(expf(p_at[0]), 0.1f);
  const float cfac     = strength / temp;
  const float eps      = 0.03f / (1.f + expf(-p_ce[0]));
  const float c2       = 0.015625f * (1.f + eps * eps);
  const float cl       = cfac * 1.4426950408889634f;   // cfac * log2(e)
  const float c2e      = c2 * cl * cl;
  const float epse     = 1e-6f * cl * cl;

  const int srow = t >> 3;
  const int sd0  = (t & 7) * 8;

  const int qg = i0 + w * 16 + lcol;      // this lane's q (global row)

  // Q fragments from global, fused doubled-phase rotation (fp32 math)
  bf16x8 qrf[2], qif[2];
  {
    const size_t base_q = ((size_t)h * S_LEN + qg) * HD;
#pragma unroll
    for (int ks = 0; ks < 2; ks++) {
      bf16x8 r8 = *(const bf16x8*)(Qr + base_q + ks * 32 + quad * 8);
      bf16x8 i8 = *(const bf16x8*)(Qi + base_q + ks * 32 + quad * 8);
      bf16x8 orr, oii;
#pragma unroll
      for (int j = 0; j < 8; j++) {
        const float2 ph = phaseTab2[h * HD + ks * 32 + quad * 8 + j];
        const float qr = bf2f((unsigned short)r8[j]);
        const float qi = bf2f((unsigned short)i8[j]);
        orr[j] = (short)f2bf(qr * ph.x - qi * ph.y);
        oii[j] = (short)f2bf(qr * ph.y + qi * ph.x);
      }
      qrf[ks] = orr;
      qif[ks] = oii;
    }
  }

  float lsum = 0.f;
  f32x4 aOr[4], aOi[4];                 // O^T: d = cc*16+quad*4+r, q = lcol
#pragma unroll
  for (int cc = 0; cc < 4; cc++)
#pragma unroll
    for (int r = 0; r < 4; r++) { aOr[cc][r] = 0.f; aOi[cc][r] = 0.f; }

  bf16x8 pk[2], pki[2], pv[2], pvi[2];

  // stride-incremented prefetch pointers (start at tile jbeg)
  const unsigned short* pKr = Kr  + ((size_t)h * S_LEN + jbeg * 64 + srow) * HD + sd0;
  const unsigned short* pKi = Ki  + ((size_t)h * S_LEN + jbeg * 64 + srow) * HD + sd0;
  const unsigned short* pVr = VtR + ((size_t)h * HD + srow) * S_LEN + jbeg * 64 + sd0;
  const unsigned short* pVi = VtI + ((size_t)h * HD + srow) * S_LEN + jbeg * 64 + sd0;

  if (jbeg < jend) {
#pragma unroll
    for (int it = 0; it < 2; it++) {
      pk [it] = *(const bf16x8*)(pKr + (size_t)it * 32 * HD);
      pki[it] = *(const bf16x8*)(pKi + (size_t)it * 32 * HD);
      pv [it] = *(const bf16x8*)(pVr + (size_t)it * 32 * S_LEN);
      pvi[it] = *(const bf16x8*)(pVi + (size_t)it * 32 * S_LEN);
    }
  }

  for (int jt = jbeg; jt < jend; jt++) {
    __syncthreads();
#pragma unroll
    for (int it = 0; it < 2; it++) {
      const int row = srow + it * 32;
      *(bf16x8*)&Krs[row * LDK + sd0] = pk [it];
      *(bf16x8*)&Kis[row * LDK + sd0] = pki[it];
      *(bf16x8*)&VTr[row * LDK + sd0] = pv [it];
      *(bf16x8*)&VTi[row * LDK + sd0] = pvi[it];
    }
    __syncthreads();

    if (jt + 1 < jend) {
      pKr += 64 * HD; pKi += 64 * HD; pVr += 64; pVi += 64;
#pragma unroll
      for (int it = 0; it < 2; it++) {
        pk [it] = *(const bf16x8*)(pKr + (size_t)it * 32 * HD);
        pki[it] = *(const bf16x8*)(pKi + (size_t)it * 32 * HD);
        pv [it] = *(const bf16x8*)(pVr + (size_t)it * 32 * S_LEN);
        pvi[it] = *(const bf16x8*)(pVi + (size_t)it * 32 * S_LEN);
      }
    }

    // ---- scores (transposed): D[kv][q] via mfma(K, Q) ----
    f32x4 k1[4], k2[4], kx[4];
#pragma unroll
    for (int cc = 0; cc < 4; cc++)
#pragma unroll
      for (int r = 0; r < 4; r++) { k1[cc][r] = 0.f; k2[cc][r] = 0.f; kx[cc][r] = 0.f; }
#pragma unroll
    for (int ks = 0; ks < 2; ks++) {
#pragma unroll
      for (int cc = 0; cc < 4; cc++) {
        const int off = (cc * 16 + lcol) * LDK + ks * 32 + quad * 8;
        bf16x8 krf = *(const bf16x8*)&Krs[off];
        bf16x8 kif = *(const bf16x8*)&Kis[off];
        k1[cc] = __builtin_amdgcn_mfma_f32_16x16x32_bf16(krf, qrf[ks], k1[cc], 0, 0, 0);
        k2[cc] = __builtin_amdgcn_mfma_f32_16x16x32_bf16(kif, qif[ks], k2[cc], 0, 0, 0);
        kx[cc] = __builtin_amdgcn_mfma_f32_16x16x32_bf16(kif, qrf[ks], kx[cc], 0, 0, 0);
        kx[cc] = __builtin_amdgcn_mfma_f32_16x16x32_bf16(krf, qif[ks], kx[cc], 0, 0, 0);
      }
    }

    __syncthreads();   // Krs/Kis reads done before Ps overwrites

    // ---- no-max softmax: p = 2^sqrt(u*c2e + epse) ----
    const int prow = (w * 16 + lcol) * LDK;
    if (jt != itile) {             // bulk tiles: no mask ops
#pragma unroll
      for (int cc = 0; cc < 4; cc++) {
        float pv4[4];
#pragma unroll
        for (int r = 0; r < 4; r++) {
          const float a = k1[cc][r] - k2[cc][r];
          const float b = kx[cc][r];
          const float u = fmaf(b, b, a * a);
          const float pp = __builtin_amdgcn_exp2f(sqrtf(fmaf(u, c2e, epse)));
          pv4[r] = pp;
          lsum += pp;
        }
        uint2 packed;
        packed.x = pack_bf16_trunc(pv4[1], pv4[0]);
        packed.y = pack_bf16_trunc(pv4[3], pv4[2]);
        *(uint2*)&Ps[prow + cc * 16 + quad * 4] = packed;
      }
    } else {                        // diagonal tile: causal mask
      const int j0 = jt * 64;
#pragma unroll
      for (int cc = 0; cc < 4; cc++) {
        float pv4[4];
#pragma unroll
        for (int r = 0; r < 4; r++) {
          const float a = k1[cc][r] - k2[cc][r];
          const float b = kx[cc][r];
          const float u = fmaf(b, b, a * a);
          float pp = __builtin_amdgcn_exp2f(sqrtf(fmaf(u, c2e, epse)));
          const int gj = j0 + cc * 16 + quad * 4 + r;
          if (gj > qg) pp = 0.f;
          pv4[r] = pp;
          lsum += pp;
        }
        uint2 packed;
        packed.x = pack_bf16_trunc(pv4[1], pv4[0]);
        packed.y = pack_bf16_trunc(pv4[3], pv4[2]);
        *(uint2*)&Ps[prow + cc * 16 + quad * 4] = packed;
      }
    }

    // ---- PV: O^T = V^T P^T ----
#pragma unroll
    for (int ks = 0; ks < 2; ks++) {
      bf16x8 pf = *(const bf16x8*)&Ps[(w * 16 + lcol) * LDK + ks * 32 + quad * 8];
#pragma unroll
      for (int cc = 0; cc < 4; cc++) {
        const int off = (cc * 16 + lcol) * LDK + ks * 32 + quad * 8;
        bf16x8 vrf = *(const bf16x8*)&VTr[off];
        bf16x8 vif = *(const bf16x8*)&VTi[off];
        aOr[cc] = __builtin_amdgcn_mfma_f32_16x16x32_bf16(vrf, pf, aOr[cc], 0, 0, 0);
        aOi[cc] = __builtin_amdgcn_mfma_f32_16x16x32_bf16(vif, pf, aOi[cc], 0, 0, 0);
      }
    }
  }

  // ---- row sums: reduce lane partials across the 4 quads (same q) ----
  lsum += __shfl_xor(lsum, 16);
  lsum += __shfl_xor(lsum, 32);
  if (lane < 16)
    Lp[((size_t)half * NH + h) * S_LEN + qg] = lsum;

  // ---- epilogue: packed unnormalized bf16 partials (O^T -> row-major) ----
  const size_t SLsz = (size_t)S_LEN * DIM;
  const size_t rowbase = half * SLsz + (size_t)qg * DIM + h * HD;
#pragma unroll
  for (int cc = 0; cc < 4; cc++) {
    const int d0 = cc * 16 + quad * 4;
    uint2 pr, pi;
    pr.x = pack_bf16_trunc(aOr[cc][1], aOr[cc][0]);
    pr.y = pack_bf16_trunc(aOr[cc][3], aOr[cc][2]);
    pi.x = pack_bf16_trunc(aOi[cc][1], aOi[cc][0]);
    pi.y = pack_bf16_trunc(aOi[cc][3], aOi[cc][2]);
    *(uint2*)(OpR + rowbase + d0) = pr;
    *(uint2*)(OpI + rowbase + d0) = pi;
  }
}

// ---------------------------------------------------------------------------
// Combine kv-split halves: O = (O0+O1)/(L0+L1), bf16 in/out.
// ---------------------------------------------------------------------------
__global__ __launch_bounds__(256) void combine_kernel(
    const unsigned short* __restrict__ OpR, const unsigned short* __restrict__ OpI,
    const float* __restrict__ Lp,
    unsigned short* __restrict__ Or, unsigned short* __restrict__ Oi)
{
  const size_t SLsz = (size_t)S_LEN * DIM;
  const int idx = blockIdx.x * 256 + threadIdx.x;
  const size_t e0 = (size_t)idx * 8;
  const int s = (int)(e0 >> 10);
  const int col = (int)(e0 & 1023);
  const int h = col >> 6;

  const float L = Lp[(size_t)h * S_LEN + s] + Lp[((size_t)NH + h) * S_LEN + s];
  const float inv = 1.f / L;

  bf16x8 r0 = *(const bf16x8*)(OpR + e0);
  bf16x8 r1 = *(const bf16x8*)(OpR + SLsz + e0);
  bf16x8 i0 = *(const bf16x8*)(OpI + e0);
  bf16x8 i1 = *(const bf16x8*)(OpI + SLsz + e0);

  u16x8 orv, oiv;
#pragma unroll
  for (int j = 0; j < 8; j++) {
    orv[j] = f2bf((bf2f((unsigned short)r0[j]) + bf2f((unsigned short)r1[j])) * inv);
    oiv[j] = f2bf((bf2f((unsigned short)i0[j]) + bf2f((unsigned short)i1[j])) * inv);
  }
  *(u16x8*)(Or + e0) = orv;
  *(u16x8*)(Oi + e0) = oiv;
}

// ---------------------------------------------------------------------------
extern "C" void kernel_launch(void* const* d_in, const int* in_sizes, int n_in,
                              void* d_out, int out_size, void* d_ws, size_t ws_size,
                              hipStream_t stream)
{
  const float* real = (const float*)d_in[0];
  const float* imag = (const float*)d_in[1];
  const float* Wq_r = (const float*)d_in[2];
  const float* bq_r = (const float*)d_in[3];
  const float* Wk_r = (const float*)d_in[4];
  const float* bk_r = (const float*)d_in[5];
  const float* Wv_r = (const float*)d_in[6];
  const float* bv_r = (const float*)d_in[7];
  const float* Wq_i = (const float*)d_in[8];
  const float* bq_i = (const float*)d_in[9];
  const float* Wk_i = (const float*)d_in[10];
  const float* bk_i = (const float*)d_in[11];
  const float* Wv_i = (const float*)d_in[12];
  const float* bv_i = (const float*)d_in[13];
  const float* Wo_r = (const float*)d_in[14];
  const float* bo_r = (const float*)d_in[15];
  const float* Wo_i = (const float*)d_in[16];
  const float* bo_i = (const float*)d_in[17];
  const float* phase = (const float*)d_in[18];
  const float* ent   = (const float*)d_in[19];
  const float* freqs = (const float*)d_in[20];
  const float* p_is  = (const float*)d_in[21];
  const float* p_at  = (const float*)d_in[22];
  const float* p_ce  = (const float*)d_in[23];

  unsigned short* ws = (unsigned short*)d_ws;
  const size_t SL = (size_t)S_LEN * DIM;
  const size_t WL = (size_t)DIM * DIM;

  unsigned short* realb = ws;
  unsigned short* imagb = realb + SL;
  unsigned short* Wb    = imagb + SL;        // 8 x WL
  unsigned short* q_r   = Wb + 8 * WL;
  unsigned short* k_r   = q_r + SL;
  unsigned short* v_r   = k_r + SL;          // [h][d][s]
  unsigned short* q_i   = v_r + SL;
  unsigned short* k_i   = q_i + SL;
  unsigned short* v_i   = k_i + SL;          // [h][d][s]
  unsigned short* OpR   = v_i + SL;          // 2 halves x SL bf16
  unsigned short* OpI   = OpR + 2 * SL;

  float* fbase    = (float*)(OpI + 2 * SL);
  float* biasf    = fbase;                   // 4096
  float* ropeTab  = biasf + 4096;            // 32768 float2
  float* phaseTb2 = ropeTab + 65536;         // 1024 float2
  float* Lp       = phaseTb2 + 2048;         // 2 * NH * S_LEN

  unsigned short* O_r = q_r;   // reuse after flash
  unsigned short* O_i = q_i;

  float* out_r = (float*)d_out;
  float* out_i = out_r + SL;

  // 0. conversions + entangle-fold + tables + folded biases (one dispatch)
  ConvBatch cb;
  cb.src[0] = real;  cb.dst[0] = realb;        cb.n[0] = (int)SL;
  cb.src[1] = imag;  cb.dst[1] = imagb;        cb.n[1] = (int)SL;
  cb.src[2] = Wv_r;  cb.dst[2] = Wb + 2 * WL;  cb.n[2] = (int)WL;
  cb.src[3] = Wv_i;  cb.dst[3] = Wb + 5 * WL;  cb.n[3] = (int)WL;
  cb.src[4] = Wo_r;  cb.dst[4] = Wb + 6 * WL;  cb.n[4] = (int)WL;
  cb.src[5] = Wo_i;  cb.dst[5] = Wb + 7 * WL;  cb.n[5] = (int)WL;
  conv_kernel<<<dim3(1024, 11), dim3(256), 0, stream>>>(
      cb, ent, freqs, phase, bq_r, bk_r, bq_i, bk_i,
      Wq_r, Wk_r, Wq_i, Wk_i, Wb,
      biasf, (float2*)ropeTab, (float2*)phaseTb2);

  // 1. six projections: Q/K head-major + fused rope (mode 3), V transposed
  BGemm g1;
  g1.A[0] = realb; g1.A[1] = realb; g1.A[2] = realb;
  g1.A[3] = imagb; g1.A[4] = imagb; g1.A[5] = imagb;
  for (int i = 0; i < 6; i++) g1.W[i] = Wb + (size_t)i * WL;
  g1.bias[0] = biasf;        g1.bias[1] = biasf + 1024; g1.bias[2] = bv_r;
  g1.bias[3] = biasf + 2048; g1.bias[4] = biasf + 3072; g1.bias[5] = bv_i;
  g1.C[0] = q_r; g1.C[1] = k_r; g1.C[2] = v_r;
  g1.C[3] = q_i; g1.C[4] = k_i; g1.C[5] = v_i;
  g1.mode[0] = 3; g1.mode[1] = 3; g1.mode[2] = 2;
  g1.mode[3] = 3; g1.mode[4] = 3; g1.mode[5] = 2;
  g1.ropeTab = (const float2*)ropeTab;
  gemm_mfma_kernel<<<dim3(8, 16, 6), dim3(256), 0, stream>>>(g1);

  // 2. flash attention (complementary-pairs mapping) -> bf16 partials
  flash_mfma_kernel<<<dim3(1024), dim3(256), 0, stream>>>(
      q_r, q_i, k_r, k_i, v_r, v_i, OpR, OpI, Lp,
      (const float2*)phaseTb2, p_is, p_at, p_ce);

  // 3. combine halves -> bf16 O
  combine_kernel<<<dim3(1024), dim3(256), 0, stream>>>(OpR, OpI, Lp, O_r, O_i);

  // 4. output projections -> fp32 d_out
  BGemm g2 = {};
  g2.A[0] = O_r; g2.A[1] = O_i;
  g2.W[0] = Wb + 6 * WL; g2.W[1] = Wb + 7 * WL;
  g2.bias[0] = bo_r; g2.bias[1] = bo_i;
  g2.C[0] = out_r; g2.C[1] = out_i;
  g2.mode[0] = 0; g2.mode[1] = 0;
  g2.ropeTab = (const float2*)ropeTab;
  gemm_mfma_kernel<<<dim3(8, 16, 2), dim3(256), 0, stream>>>(g2);
}

// Round 15
// 273.377 us; speedup vs baseline: 1.0522x; 1.0267x over previous
//
#include <hip/hip_runtime.h>
#include <cstddef>
#include <cstdint>
#include <math.h>

#define S_LEN 2048
#define DIM 1024
#define NH 16
#define HD 64

typedef __attribute__((ext_vector_type(8))) short bf16x8;
typedef __attribute__((ext_vector_type(8))) unsigned short u16x8;
typedef __attribute__((ext_vector_type(4))) float f32x4;

__device__ inline unsigned short f2bf(float x) {
  union { float f; unsigned u; } v; v.f = x;
  unsigned r = v.u + 0x7FFFu + ((v.u >> 16) & 1u);   // round-to-nearest-even
  return (unsigned short)(r >> 16);
}
__device__ inline float bf2f(unsigned short x) {
  union { unsigned u; float f; } v; v.u = ((unsigned)x) << 16; return v.f;
}
// pack two f32 -> two bf16 (truncation) in one v_perm_b32: out = {hi.bf16, lo.bf16}
__device__ inline unsigned pack_bf16_trunc(float hi, float lo) {
  union { float f; unsigned u; } a, b;
  a.f = hi; b.f = lo;
  return __builtin_amdgcn_perm(a.u, b.u, 0x07060302u);
}

#define GLOAD_LDS16(g, l)                                              \
  __builtin_amdgcn_global_load_lds(                                    \
      (const __attribute__((address_space(1))) void*)(g),              \
      (__attribute__((address_space(3))) void*)(l), 16, 0, 0)

// ---------------------------------------------------------------------------
// conv kernel: y=0..5 plain fp32->bf16 (real, imag, Wv_r, Wv_i, Wo_r, Wo_i).
// y=6: misc precompute (rope table, doubled phase table, folded biases).
// y=7..10: entangle-fold of Wq_r/Wk_r/Wq_i/Wk_i (d-major, 1x read amp).
// ---------------------------------------------------------------------------
struct ConvBatch {
  const float* src[6];
  unsigned short* dst[6];
  int n[6];
};

__global__ __launch_bounds__(256) void conv_kernel(
    ConvBatch cb, const float* __restrict__ E,
    const float* __restrict__ freqs, const float* __restrict__ phase,
    const float* __restrict__ bq_r, const float* __restrict__ bk_r,
    const float* __restrict__ bq_i, const float* __restrict__ bk_i,
    const float* __restrict__ Wq_r, const float* __restrict__ Wk_r,
    const float* __restrict__ Wq_i, const float* __restrict__ Wk_i,
    unsigned short* __restrict__ Wb,
    float* __restrict__ biasf, float2* __restrict__ ropeTab,
    float2* __restrict__ phaseTab2)
{
  const int t = threadIdx.x;
  const int y = blockIdx.y;

  if (y == 6) {   // misc precompute slice
    __shared__ float Es[NH * NH];
    Es[t] = E[t];
    __syncthreads();
    const int idx = blockIdx.x * 256 + t;
    if (idx < 32768) {
      const int s = idx >> 4, j = idx & 15;
      float sn, cs;
      sincosf((float)s * freqs[j], &sn, &cs);
      ropeTab[idx] = make_float2(cs, sn);
    } else if (idx < 32768 + 1024) {
      const int k = idx - 32768;
      float sn, cs;
      sincosf(2.f * phase[k], &sn, &cs);
      phaseTab2[k] = make_float2(cs, sn);
    } else if (idx < 32768 + 1024 + 4096) {
      const int i = idx - 33792;
      const int tz = i >> 10, nn = i & 1023;
      const int x = nn >> 6, d = nn & 63;
      const float* b = (tz == 0) ? bq_r : (tz == 1) ? bk_r : (tz == 2) ? bq_i : bk_i;
      float acc = 0.f;
#pragma unroll
      for (int h = 0; h < NH; h++) acc += Es[h * NH + x] * b[h * 64 + d];
      biasf[i] = acc;
    }
    return;
  }

  if (y >= 7) {   // entangle-fold slices, wi = y-7
    if (blockIdx.x >= 64) return;
    __shared__ float Es2[NH * NH];
    Es2[t] = E[t];
    __syncthreads();
    const int d  = blockIdx.x;
    const int wi = y - 7;
    const float* src = (wi == 0) ? Wq_r : (wi == 1) ? Wk_r : (wi == 2) ? Wq_i : Wk_i;
    const int slot   = (wi == 0) ? 0 : (wi == 1) ? 1 : (wi == 2) ? 3 : 4;
    unsigned short* dst = Wb + (size_t)slot * DIM * DIM;

    const int k0 = t * 4;
    float4 in[NH];
#pragma unroll
    for (int h = 0; h < NH; h++)
      in[h] = *(const float4*)(src + ((size_t)(h * 64 + d) << 10) + k0);

#pragma unroll
    for (int x = 0; x < NH; x++) {
      float ax = 0.f, ay = 0.f, az = 0.f, aw = 0.f;
#pragma unroll
      for (int h = 0; h < NH; h++) {
        const float e = Es2[h * NH + x];
        ax += e * in[h].x; ay += e * in[h].y;
        az += e * in[h].z; aw += e * in[h].w;
      }
      ushort4 o;
      o.x = f2bf(ax); o.y = f2bf(ay); o.z = f2bf(az); o.w = f2bf(aw);
      *(ushort4*)(dst + ((size_t)(x * 64 + d) << 10) + k0) = o;
    }
    return;
  }

  const int flat = (blockIdx.x * 256 + t) * 8;
  if (flat >= cb.n[y]) return;
  const float* s = cb.src[y];
  float4 a = *(const float4*)(s + flat);
  float4 b = *(const float4*)(s + flat + 4);
  u16x8 o;
  o[0] = f2bf(a.x); o[1] = f2bf(a.y); o[2] = f2bf(a.z); o[3] = f2bf(a.w);
  o[4] = f2bf(b.x); o[5] = f2bf(b.y); o[6] = f2bf(b.z); o[7] = f2bf(b.w);
  *(u16x8*)(cb.dst[y] + flat) = o;
}

// ---------------------------------------------------------------------------
// bf16 MFMA GEMM: C = A @ W^T + bias. Output modes (per z):
//   0: fp32 row-major (s, DIM)
//   2: bf16 transposed head-major [h][d][s]   (V)
//   3: bf16 head-major [h][s][d] + fused RoPE (fp32, shfl_xor pair mix) (Q,K)
// ---------------------------------------------------------------------------
struct BGemm {
  const unsigned short* A[6];
  const unsigned short* W[6];
  const float* bias[6];
  void* C[6];
  int mode[6];
  const float2* ropeTab;
};

__global__ __launch_bounds__(256) void gemm_mfma_kernel(BGemm gb)
{
  constexpr int K = DIM;
  const int z = blockIdx.z;
  const unsigned short* __restrict__ A = gb.A[z];
  const unsigned short* __restrict__ W = gb.W[z];
  const float* __restrict__ bias = gb.bias[z];
  const int mode = gb.mode[z];

  __shared__ __align__(16) unsigned short As[128 * 32];
  __shared__ __align__(16) unsigned short Ws[128 * 32];

  const int t    = threadIdx.x;
  const int lane = t & 63;
  const int w    = t >> 6;
  const int wm   = w >> 1, wn = w & 1;
  const int quad = lane >> 4, lcol = lane & 15;
  const int m0   = blockIdx.y * 128;
  const int n0   = blockIdx.x * 128;

  const int srow = t >> 2;
  const int sk8  = (t & 3) * 8;

  f32x4 acc[4][4];
#pragma unroll
  for (int i = 0; i < 4; i++)
#pragma unroll
    for (int j = 0; j < 4; j++)
#pragma unroll
      for (int r = 0; r < 4; r++) acc[i][j][r] = 0.f;

  for (int k0 = 0; k0 < K; k0 += 32) {
    __syncthreads();
#pragma unroll
    for (int p = 0; p < 2; p++) {
      const unsigned short* ga = A + (size_t)(m0 + p * 64 + srow) * K + k0 + sk8;
      GLOAD_LDS16(ga, As + (size_t)(p * 256 + w * 64) * 8);
      const unsigned short* gw = W + (size_t)(n0 + p * 64 + srow) * K + k0 + sk8;
      GLOAD_LDS16(gw, Ws + (size_t)(p * 256 + w * 64) * 8);
    }
    __syncthreads();

    bf16x8 af[4], bfr[4];
#pragma unroll
    for (int mi = 0; mi < 4; mi++)
      af[mi] = *(const bf16x8*)&As[(wm * 64 + mi * 16 + lcol) * 32 + quad * 8];
#pragma unroll
    for (int ni = 0; ni < 4; ni++)
      bfr[ni] = *(const bf16x8*)&Ws[(wn * 64 + ni * 16 + lcol) * 32 + quad * 8];
#pragma unroll
    for (int mi = 0; mi < 4; mi++)
#pragma unroll
      for (int ni = 0; ni < 4; ni++)
        acc[mi][ni] = __builtin_amdgcn_mfma_f32_16x16x32_bf16(af[mi], bfr[ni], acc[mi][ni], 0, 0, 0);
  }

#pragma unroll
  for (int mi = 0; mi < 4; mi++) {
#pragma unroll
    for (int ni = 0; ni < 4; ni++) {
#pragma unroll
      for (int r = 0; r < 4; r++) {
        const int grow = m0 + wm * 64 + mi * 16 + quad * 4 + r;
        const int gcol = n0 + wn * 64 + ni * 16 + lcol;
        float v = acc[mi][ni][r] + bias[gcol];
        if (mode == 3) {
          const float vp = __shfl_xor(v, 1);   // partner column (gcol^1)
          const int d = gcol & 63;
          if (d < 32) {
            const float2 cs = gb.ropeTab[grow * 16 + (d >> 1)];
            v = (d & 1) ? (v * cs.x + vp * cs.y)
                        : (v * cs.x - vp * cs.y);
          }
        }
        if (mode == 0) {
          ((float*)gb.C[z])[(size_t)grow * DIM + gcol] = v;
        } else if (mode == 2) {
          const int hh = gcol >> 6, d = gcol & 63;
          ((unsigned short*)gb.C[z])[((size_t)hh * HD + d) * S_LEN + grow] = f2bf(v);
        } else {
          const int hh = gcol >> 6, d = gcol & 63;
          ((unsigned short*)gb.C[z])[((size_t)hh * S_LEN + grow) * HD + d] = f2bf(v);
        }
      }
    }
  }
}

// ---------------------------------------------------------------------------
// Flash attention, transposed scores (D[kv][q] via mfma(K,Q)), kv-split,
// no-max softmax. R12 configuration (best measured): pair p = bx>>1
// (itile = 31-(p>>4) heavy-first, h = p&15), half = bx&1.
// ---------------------------------------------------------------------------
#define LDK 72

__global__ __launch_bounds__(256) void flash_mfma_kernel(
    const unsigned short* __restrict__ Qr, const unsigned short* __restrict__ Qi,
    const unsigned short* __restrict__ Kr, const unsigned short* __restrict__ Ki,
    const unsigned short* __restrict__ VtR, const unsigned short* __restrict__ VtI,
    unsigned short* __restrict__ OpR, unsigned short* __restrict__ OpI,
    float* __restrict__ Lp, const float2* __restrict__ phaseTab2,
    const float* __restrict__ p_is, const float* __restrict__ p_at,
    const float* __restrict__ p_ce)
{
  __shared__ __align__(16) unsigned short Krs[64 * LDK];
  __shared__ __align__(16) unsigned short Kis[64 * LDK];
  __shared__ __align__(16) unsigned short VTr[64 * LDK];
  __shared__ __align__(16) unsigned short VTi[64 * LDK];
  unsigned short* Ps = Krs;   // alias: Krs dead after scores (barrier-protected)

  const int t    = threadIdx.x;
  const int lane = t & 63;
  const int w    = t >> 6;
  const int quad = lane >> 4;
  const int lcol = lane & 15;

  const int bx    = blockIdx.x;
  const int p     = bx >> 1;
  const int half  = bx & 1;
  const int itile = 31 - (p >> 4);     // heavy-first
  const int h     = p & 15;
  const int i0    = itile * 64;
  const int n     = itile + 1;
  const int jmid  = (n + 1) >> 1;
  const int jbeg  = half ? jmid : 0;
  const int jend  = half ? n : jmid;

  const float strength = 1.f / (1.f + expf(-p_is[0]));
  const float temp     = fmaxf(expf(p_at[0]), 0.1f);
  const float cfac     = strength / temp;
  const float eps      = 0.03f / (1.f + expf(-p_ce[0]));
  const float c2       = 0.015625f * (1.f + eps * eps);
  const float cl       = cfac * 1.4426950408889634f;   // cfac * log2(e)
  const float c2e      = c2 * cl * cl;
  const float epse     = 1e-6f * cl * cl;

  const int srow = t >> 3;
  const int sd0  = (t & 7) * 8;

  const int qg = i0 + w * 16 + lcol;      // this lane's q (global row)

  // Q fragments from global, fused doubled-phase rotation (fp32 math)
  bf16x8 qrf[2], qif[2];
  {
    const size_t base_q = ((size_t)h * S_LEN + qg) * HD;
#pragma unroll
    for (int ks = 0; ks < 2; ks++) {
      bf16x8 r8 = *(const bf16x8*)(Qr + base_q + ks * 32 + quad * 8);
      bf16x8 i8 = *(const bf16x8*)(Qi + base_q + ks * 32 + quad * 8);
      bf16x8 orr, oii;
#pragma unroll
      for (int j = 0; j < 8; j++) {
        const float2 ph = phaseTab2[h * HD + ks * 32 + quad * 8 + j];
        const float qr = bf2f((unsigned short)r8[j]);
        const float qi = bf2f((unsigned short)i8[j]);
        orr[j] = (short)f2bf(qr * ph.x - qi * ph.y);
        oii[j] = (short)f2bf(qr * ph.y + qi * ph.x);
      }
      qrf[ks] = orr;
      qif[ks] = oii;
    }
  }

  float lsum = 0.f;
  f32x4 aOr[4], aOi[4];                 // O^T: d = cc*16+quad*4+r, q = lcol
#pragma unroll
  for (int cc = 0; cc < 4; cc++)
#pragma unroll
    for (int r = 0; r < 4; r++) { aOr[cc][r] = 0.f; aOi[cc][r] = 0.f; }

  bf16x8 pk[2], pki[2], pv[2], pvi[2];

  // stride-incremented prefetch pointers (start at tile jbeg)
  const unsigned short* pKr = Kr  + ((size_t)h * S_LEN + jbeg * 64 + srow) * HD + sd0;
  const unsigned short* pKi = Ki  + ((size_t)h * S_LEN + jbeg * 64 + srow) * HD + sd0;
  const unsigned short* pVr = VtR + ((size_t)h * HD + srow) * S_LEN + jbeg * 64 + sd0;
  const unsigned short* pVi = VtI + ((size_t)h * HD + srow) * S_LEN + jbeg * 64 + sd0;

  if (jbeg < jend) {
#pragma unroll
    for (int it = 0; it < 2; it++) {
      pk [it] = *(const bf16x8*)(pKr + (size_t)it * 32 * HD);
      pki[it] = *(const bf16x8*)(pKi + (size_t)it * 32 * HD);
      pv [it] = *(const bf16x8*)(pVr + (size_t)it * 32 * S_LEN);
      pvi[it] = *(const bf16x8*)(pVi + (size_t)it * 32 * S_LEN);
    }
  }

  for (int jt = jbeg; jt < jend; jt++) {
    __syncthreads();
#pragma unroll
    for (int it = 0; it < 2; it++) {
      const int row = srow + it * 32;
      *(bf16x8*)&Krs[row * LDK + sd0] = pk [it];
      *(bf16x8*)&Kis[row * LDK + sd0] = pki[it];
      *(bf16x8*)&VTr[row * LDK + sd0] = pv [it];
      *(bf16x8*)&VTi[row * LDK + sd0] = pvi[it];
    }
    __syncthreads();

    if (jt + 1 < jend) {
      pKr += 64 * HD; pKi += 64 * HD; pVr += 64; pVi += 64;
#pragma unroll
      for (int it = 0; it < 2; it++) {
        pk [it] = *(const bf16x8*)(pKr + (size_t)it * 32 * HD);
        pki[it] = *(const bf16x8*)(pKi + (size_t)it * 32 * HD);
        pv [it] = *(const bf16x8*)(pVr + (size_t)it * 32 * S_LEN);
        pvi[it] = *(const bf16x8*)(pVi + (size_t)it * 32 * S_LEN);
      }
    }

    // ---- scores (transposed): D[kv][q] via mfma(K, Q) ----
    f32x4 k1[4], k2[4], kx[4];
#pragma unroll
    for (int cc = 0; cc < 4; cc++)
#pragma unroll
      for (int r = 0; r < 4; r++) { k1[cc][r] = 0.f; k2[cc][r] = 0.f; kx[cc][r] = 0.f; }
#pragma unroll
    for (int ks = 0; ks < 2; ks++) {
#pragma unroll
      for (int cc = 0; cc < 4; cc++) {
        const int off = (cc * 16 + lcol) * LDK + ks * 32 + quad * 8;
        bf16x8 krf = *(const bf16x8*)&Krs[off];
        bf16x8 kif = *(const bf16x8*)&Kis[off];
        k1[cc] = __builtin_amdgcn_mfma_f32_16x16x32_bf16(krf, qrf[ks], k1[cc], 0, 0, 0);
        k2[cc] = __builtin_amdgcn_mfma_f32_16x16x32_bf16(kif, qif[ks], k2[cc], 0, 0, 0);
        kx[cc] = __builtin_amdgcn_mfma_f32_16x16x32_bf16(kif, qrf[ks], kx[cc], 0, 0, 0);
        kx[cc] = __builtin_amdgcn_mfma_f32_16x16x32_bf16(krf, qif[ks], kx[cc], 0, 0, 0);
      }
    }

    __syncthreads();   // Krs/Kis reads done before Ps overwrites

    // ---- no-max softmax: p = 2^sqrt(u*c2e + epse) ----
    const int prow = (w * 16 + lcol) * LDK;
    if (jt != itile) {             // bulk tiles: no mask ops
#pragma unroll
      for (int cc = 0; cc < 4; cc++) {
        float pv4[4];
#pragma unroll
        for (int r = 0; r < 4; r++) {
          const float a = k1[cc][r] - k2[cc][r];
          const float b = kx[cc][r];
          const float u = fmaf(b, b, a * a);
          const float pp = __builtin_amdgcn_exp2f(sqrtf(fmaf(u, c2e, epse)));
          pv4[r] = pp;
          lsum += pp;
        }
        uint2 packed;
        packed.x = pack_bf16_trunc(pv4[1], pv4[0]);
        packed.y = pack_bf16_trunc(pv4[3], pv4[2]);
        *(uint2*)&Ps[prow + cc * 16 + quad * 4] = packed;
      }
    } else {                        // diagonal tile: causal mask
      const int j0 = jt * 64;
#pragma unroll
      for (int cc = 0; cc < 4; cc++) {
        float pv4[4];
#pragma unroll
        for (int r = 0; r < 4; r++) {
          const float a = k1[cc][r] - k2[cc][r];
          const float b = kx[cc][r];
          const float u = fmaf(b, b, a * a);
          float pp = __builtin_amdgcn_exp2f(sqrtf(fmaf(u, c2e, epse)));
          const int gj = j0 + cc * 16 + quad * 4 + r;
          if (gj > qg) pp = 0.f;
          pv4[r] = pp;
          lsum += pp;
        }
        uint2 packed;
        packed.x = pack_bf16_trunc(pv4[1], pv4[0]);
        packed.y = pack_bf16_trunc(pv4[3], pv4[2]);
        *(uint2*)&Ps[prow + cc * 16 + quad * 4] = packed;
      }
    }

    // ---- PV: O^T = V^T P^T ----
#pragma unroll
    for (int ks = 0; ks < 2; ks++) {
      bf16x8 pf = *(const bf16x8*)&Ps[(w * 16 + lcol) * LDK + ks * 32 + quad * 8];
#pragma unroll
      for (int cc = 0; cc < 4; cc++) {
        const int off = (cc * 16 + lcol) * LDK + ks * 32 + quad * 8;
        bf16x8 vrf = *(const bf16x8*)&VTr[off];
        bf16x8 vif = *(const bf16x8*)&VTi[off];
        aOr[cc] = __builtin_amdgcn_mfma_f32_16x16x32_bf16(vrf, pf, aOr[cc], 0, 0, 0);
        aOi[cc] = __builtin_amdgcn_mfma_f32_16x16x32_bf16(vif, pf, aOi[cc], 0, 0, 0);
      }
    }
  }

  // ---- row sums: reduce lane partials across the 4 quads (same q) ----
  lsum += __shfl_xor(lsum, 16);
  lsum += __shfl_xor(lsum, 32);
  if (lane < 16)
    Lp[((size_t)half * NH + h) * S_LEN + qg] = lsum;

  // ---- epilogue: packed unnormalized bf16 partials (O^T -> row-major) ----
  const size_t SLsz = (size_t)S_LEN * DIM;
  const size_t rowbase = half * SLsz + (size_t)qg * DIM + h * HD;
#pragma unroll
  for (int cc = 0; cc < 4; cc++) {
    const int d0 = cc * 16 + quad * 4;
    uint2 pr, pi;
    pr.x = pack_bf16_trunc(aOr[cc][1], aOr[cc][0]);
    pr.y = pack_bf16_trunc(aOr[cc][3], aOr[cc][2]);
    pi.x = pack_bf16_trunc(aOi[cc][1], aOi[cc][0]);
    pi.y = pack_bf16_trunc(aOi[cc][3], aOi[cc][2]);
    *(uint2*)(OpR + rowbase + d0) = pr;
    *(uint2*)(OpI + rowbase + d0) = pi;
  }
}

// ---------------------------------------------------------------------------
// Combine kv-split halves: O = (O0+O1)/(L0+L1), bf16 in/out.
// ---------------------------------------------------------------------------
__global__ __launch_bounds__(256) void combine_kernel(
    const unsigned short* __restrict__ OpR, const unsigned short* __restrict__ OpI,
    const float* __restrict__ Lp,
    unsigned short* __restrict__ Or, unsigned short* __restrict__ Oi)
{
  const size_t SLsz = (size_t)S_LEN * DIM;
  const int idx = blockIdx.x * 256 + threadIdx.x;
  const size_t e0 = (size_t)idx * 8;
  const int s = (int)(e0 >> 10);
  const int col = (int)(e0 & 1023);
  const int h = col >> 6;

  const float L = Lp[(size_t)h * S_LEN + s] + Lp[((size_t)NH + h) * S_LEN + s];
  const float inv = 1.f / L;

  bf16x8 r0 = *(const bf16x8*)(OpR + e0);
  bf16x8 r1 = *(const bf16x8*)(OpR + SLsz + e0);
  bf16x8 i0 = *(const bf16x8*)(OpI + e0);
  bf16x8 i1 = *(const bf16x8*)(OpI + SLsz + e0);

  u16x8 orv, oiv;
#pragma unroll
  for (int j = 0; j < 8; j++) {
    orv[j] = f2bf((bf2f((unsigned short)r0[j]) + bf2f((unsigned short)r1[j])) * inv);
    oiv[j] = f2bf((bf2f((unsigned short)i0[j]) + bf2f((unsigned short)i1[j])) * inv);
  }
  *(u16x8*)(Or + e0) = orv;
  *(u16x8*)(Oi + e0) = oiv;
}

// ---------------------------------------------------------------------------
extern "C" void kernel_launch(void* const* d_in, const int* in_sizes, int n_in,
                              void* d_out, int out_size, void* d_ws, size_t ws_size,
                              hipStream_t stream)
{
  const float* real = (const float*)d_in[0];
  const float* imag = (const float*)d_in[1];
  const float* Wq_r = (const float*)d_in[2];
  const float* bq_r = (const float*)d_in[3];
  const float* Wk_r = (const float*)d_in[4];
  const float* bk_r = (const float*)d_in[5];
  const float* Wv_r = (const float*)d_in[6];
  const float* bv_r = (const float*)d_in[7];
  const float* Wq_i = (const float*)d_in[8];
  const float* bq_i = (const float*)d_in[9];
  const float* Wk_i = (const float*)d_in[10];
  const float* bk_i = (const float*)d_in[11];
  const float* Wv_i = (const float*)d_in[12];
  const float* bv_i = (const float*)d_in[13];
  const float* Wo_r = (const float*)d_in[14];
  const float* bo_r = (const float*)d_in[15];
  const float* Wo_i = (const float*)d_in[16];
  const float* bo_i = (const float*)d_in[17];
  const float* phase = (const float*)d_in[18];
  const float* ent   = (const float*)d_in[19];
  const float* freqs = (const float*)d_in[20];
  const float* p_is  = (const float*)d_in[21];
  const float* p_at  = (const float*)d_in[22];
  const float* p_ce  = (const float*)d_in[23];

  unsigned short* ws = (unsigned short*)d_ws;
  const size_t SL = (size_t)S_LEN * DIM;
  const size_t WL = (size_t)DIM * DIM;

  unsigned short* realb = ws;
  unsigned short* imagb = realb + SL;
  unsigned short* Wb    = imagb + SL;        // 8 x WL
  unsigned short* q_r   = Wb + 8 * WL;
  unsigned short* k_r   = q_r + SL;
  unsigned short* v_r   = k_r + SL;          // [h][d][s]
  unsigned short* q_i   = v_r + SL;
  unsigned short* k_i   = q_i + SL;
  unsigned short* v_i   = k_i + SL;          // [h][d][s]
  unsigned short* OpR   = v_i + SL;          // 2 halves x SL bf16
  unsigned short* OpI   = OpR + 2 * SL;

  float* fbase    = (float*)(OpI + 2 * SL);
  float* biasf    = fbase;                   // 4096
  float* ropeTab  = biasf + 4096;            // 32768 float2
  float* phaseTb2 = ropeTab + 65536;         // 1024 float2
  float* Lp       = phaseTb2 + 2048;         // 2 * NH * S_LEN

  unsigned short* O_r = q_r;   // reuse after flash
  unsigned short* O_i = q_i;

  float* out_r = (float*)d_out;
  float* out_i = out_r + SL;

  // 0. conversions + entangle-fold + tables + folded biases (one dispatch)
  ConvBatch cb;
  cb.src[0] = real;  cb.dst[0] = realb;        cb.n[0] = (int)SL;
  cb.src[1] = imag;  cb.dst[1] = imagb;        cb.n[1] = (int)SL;
  cb.src[2] = Wv_r;  cb.dst[2] = Wb + 2 * WL;  cb.n[2] = (int)WL;
  cb.src[3] = Wv_i;  cb.dst[3] = Wb + 5 * WL;  cb.n[3] = (int)WL;
  cb.src[4] = Wo_r;  cb.dst[4] = Wb + 6 * WL;  cb.n[4] = (int)WL;
  cb.src[5] = Wo_i;  cb.dst[5] = Wb + 7 * WL;  cb.n[5] = (int)WL;
  conv_kernel<<<dim3(1024, 11), dim3(256), 0, stream>>>(
      cb, ent, freqs, phase, bq_r, bk_r, bq_i, bk_i,
      Wq_r, Wk_r, Wq_i, Wk_i, Wb,
      biasf, (float2*)ropeTab, (float2*)phaseTb2);

  // 1. six projections: Q/K head-major + fused rope (mode 3), V transposed
  BGemm g1;
  g1.A[0] = realb; g1.A[1] = realb; g1.A[2] = realb;
  g1.A[3] = imagb; g1.A[4] = imagb; g1.A[5] = imagb;
  for (int i = 0; i < 6; i++) g1.W[i] = Wb + (size_t)i * WL;
  g1.bias[0] = biasf;        g1.bias[1] = biasf + 1024; g1.bias[2] = bv_r;
  g1.bias[3] = biasf + 2048; g1.bias[4] = biasf + 3072; g1.bias[5] = bv_i;
  g1.C[0] = q_r; g1.C[1] = k_r; g1.C[2] = v_r;
  g1.C[3] = q_i; g1.C[4] = k_i; g1.C[5] = v_i;
  g1.mode[0] = 3; g1.mode[1] = 3; g1.mode[2] = 2;
  g1.mode[3] = 3; g1.mode[4] = 3; g1.mode[5] = 2;
  g1.ropeTab = (const float2*)ropeTab;
  gemm_mfma_kernel<<<dim3(8, 16, 6), dim3(256), 0, stream>>>(g1);

  // 2. flash attention (R12 mapping) -> bf16 partials
  flash_mfma_kernel<<<dim3(1024), dim3(256), 0, stream>>>(
      q_r, q_i, k_r, k_i, v_r, v_i, OpR, OpI, Lp,
      (const float2*)phaseTb2, p_is, p_at, p_ce);

  // 3. combine halves -> bf16 O
  combine_kernel<<<dim3(1024), dim3(256), 0, stream>>>(OpR, OpI, Lp, O_r, O_i);

  // 4. output projections -> fp32 d_out
  BGemm g2 = {};
  g2.A[0] = O_r; g2.A[1] = O_i;
  g2.W[0] = Wb + 6 * WL; g2.W[1] = Wb + 7 * WL;
  g2.bias[0] = bo_r; g2.bias[1] = bo_i;
  g2.C[0] = out_r; g2.C[1] = out_i;
  g2.mode[0] = 0; g2.mode[1] = 0;
  g2.ropeTab = (const float2*)ropeTab;
  gemm_mfma_kernel<<<dim3(8, 16, 2), dim3(256), 0, stream>>>(g2);
}